// Round 5
// baseline (631.156 us; speedup 1.0000x reference)
//
#include <hip/hip_runtime.h>

#define D       128
#define NNODES  50000
#define NEDGES  600000
#define TEE     128          // edges per block (edge kernel)
#define TN      64           // nodes per block (node kernel)
#define BLK     256
#define LN_EPS  1e-5f

typedef float  fx4    __attribute__((ext_vector_type(4)));
typedef float  f32x4  __attribute__((ext_vector_type(4)));
typedef __bf16 bf16x4 __attribute__((ext_vector_type(4)));
typedef __bf16 bf16x8 __attribute__((ext_vector_type(8)));

// ---- d_ws layout (bf16 elements) ----
// Fragment-major weights: frag[kstep][nf][lane(64)][8], 512 bf16 per frag.
#define EW1F_OFF 0                         // K=384: 12 ksteps * 8 nf
#define EW2F_OFF (128 * 384)               // K=128:  4 ksteps * 8 nf
#define NW1F_OFF (EW2F_OFF + 128 * 128)    // K=256:  8 ksteps * 8 nf
#define NW2F_OFF (NW1F_OFF + 128 * 256)    // K=128
#define WS_ELEMS (NW2F_OFF + 128 * 128)    // 114688 bf16

__device__ __forceinline__ float silu_f(float z) {
    return z * (1.0f / (1.0f + __expf(-z)));
}

// ---------------------------------------------------------------------------
// Weight prep: f32 [K][128] -> bf16 fragment-major.
// frag f = ks*8+nf ; lane l ; elem j  maps to  n = nf*16+(l&15),
// k = ks*32 + (l>>4)*8 + j.  Stored at  base + f*512 + l*8 + j.
// ---------------------------------------------------------------------------
__global__ __launch_bounds__(256) void prep_weights(
    const float* __restrict__ eW1, const float* __restrict__ eW2,
    const float* __restrict__ nW1, const float* __restrict__ nW2,
    __bf16* __restrict__ ws)
{
    int idx = blockIdx.x * 256 + threadIdx.x;
    if (idx >= WS_ELEMS) return;
    const float* src;
    int local;
    if (idx < EW2F_OFF)      { src = eW1; local = idx; }
    else if (idx < NW1F_OFF) { src = eW2; local = idx - EW2F_OFF; }
    else if (idx < NW2F_OFF) { src = nW1; local = idx - NW1F_OFF; }
    else                     { src = nW2; local = idx - NW2F_OFF; }
    const int f   = local >> 9;          // frag index
    const int rem = local & 511;
    const int l   = rem >> 3;            // lane
    const int j   = rem & 7;             // elem
    const int ks  = f >> 3;
    const int nf  = f & 7;
    const int n   = (nf << 4) + (l & 15);
    const int k   = (ks << 5) + ((l >> 4) << 3) + j;
    ws[idx] = (__bf16)src[(size_t)k * D + n];
}

// ---------------------------------------------------------------------------
// Edge kernel: 128 edges/block, 4 waves x 32 rows (M=32 per wave).
// K=384 staged segment-at-a-time (3 x 128 cols) into one LDS buffer;
// h1 aliases the same buffer after GEMM1 (wave-private rows).
// ---------------------------------------------------------------------------
__global__ __launch_bounds__(BLK) void edge_kernel(
    const float* __restrict__ x,
    const float* __restrict__ edge_attr,
    const int*   __restrict__ edge_index,
    const __bf16* __restrict__ W1f,
    const float* __restrict__ b1,
    const __bf16* __restrict__ W2f,
    const float* __restrict__ b2,
    const float* __restrict__ lng, const float* __restrict__ lnb,
    float* __restrict__ edges_out,
    float* __restrict__ agg)
{
    __shared__ __bf16 seg[TEE][136];   // 128 cols used; h1 aliases later
    __shared__ int    src_s[TEE], dst_s[TEE];

    const int tid = threadIdx.x;
    const int e0g = blockIdx.x * TEE;

    if (tid < TEE) {
        const int ge = e0g + tid;
        src_s[tid] = (ge < NEDGES) ? edge_index[ge] : 0;            // src (j)
        dst_s[tid] = (ge < NEDGES) ? edge_index[NEDGES + ge] : 0;   // dst (i)
    }

    const int lane  = tid & 63;
    const int wid   = tid >> 6;
    const int wrow0 = wid << 5;        // wave's 32 rows
    const int c16   = lane & 15;
    const int kq    = lane >> 4;
    const int ks8   = kq << 3;
    const int lo8   = lane << 3;       // fragment lane offset (bf16 elems)

    f32x4 acc[2][8];
    #pragma unroll
    for (int mi = 0; mi < 2; ++mi)
        #pragma unroll
        for (int nf = 0; nf < 8; ++nf) acc[mi][nf] = (f32x4){0.f, 0.f, 0.f, 0.f};

    // ---- GEMM1 over 3 K-segments: 0=x[dst], 1=x[src], 2=edge_attr ----
    #pragma unroll
    for (int sgi = 0; sgi < 3; ++sgi) {
        __syncthreads();               // prior phase done reading seg
        // stage this 128-col segment: 128 rows x 32 fx4
        #pragma unroll
        for (int it = 0; it < 16; ++it) {
            const int idx = tid + it * BLK;
            const int e   = idx >> 5;
            const int c4  = (idx & 31) << 2;
            fx4 v;
            if (sgi == 0)      v = *(const fx4*)&x[(size_t)dst_s[e] * D + c4];
            else if (sgi == 1) v = *(const fx4*)&x[(size_t)src_s[e] * D + c4];
            else {
                const int ge = e0g + e;
                if (ge < NEDGES) v = *(const fx4*)&edge_attr[(size_t)ge * D + c4];
                else             v = (fx4){0.f, 0.f, 0.f, 0.f};
            }
            bf16x4 h;
            #pragma unroll
            for (int j = 0; j < 4; ++j) h[j] = (__bf16)v[j];
            *(bf16x4*)&seg[e][c4] = h;
        }
        __syncthreads();

        #pragma unroll
        for (int ks2 = 0; ks2 < 4; ++ks2) {
            bf16x8 a0 = *(const bf16x8*)&seg[wrow0 + c16][(ks2 << 5) + ks8];
            bf16x8 a1 = *(const bf16x8*)&seg[wrow0 + 16 + c16][(ks2 << 5) + ks8];
            const __bf16* wp = W1f + ((size_t)((sgi * 4 + ks2) << 3) << 9) + lo8;
            #pragma unroll
            for (int nf = 0; nf < 8; ++nf) {
                bf16x8 b = *(const bf16x8*)(wp + (nf << 9));
                acc[0][nf] = __builtin_amdgcn_mfma_f32_16x16x32_bf16(a0, b, acc[0][nf], 0, 0, 0);
                acc[1][nf] = __builtin_amdgcn_mfma_f32_16x16x32_bf16(a1, b, acc[1][nf], 0, 0, 0);
            }
        }
    }

    // SiLU + bias -> h1 aliased into seg cols 0..127 (wave-private rows:
    // each wave reads/writes only rows wrow0..wrow0+31, so no barrier)
    #pragma unroll
    for (int nf = 0; nf < 8; ++nf) {
        const float bb = b1[nf * 16 + c16];
        #pragma unroll
        for (int mi = 0; mi < 2; ++mi)
            #pragma unroll
            for (int r = 0; r < 4; ++r) {
                float h = silu_f(acc[mi][nf][r] + bb);
                seg[wrow0 + mi * 16 + kq * 4 + r][nf * 16 + c16] = (__bf16)h;
            }
    }

    // ---- GEMM2: [32,128] @ [128,128] per wave ----
    f32x4 acc2[2][8];
    #pragma unroll
    for (int mi = 0; mi < 2; ++mi)
        #pragma unroll
        for (int nf = 0; nf < 8; ++nf) acc2[mi][nf] = (f32x4){0.f, 0.f, 0.f, 0.f};

    #pragma unroll
    for (int ks = 0; ks < 4; ++ks) {
        bf16x8 a0 = *(const bf16x8*)&seg[wrow0 + c16][(ks << 5) + ks8];
        bf16x8 a1 = *(const bf16x8*)&seg[wrow0 + 16 + c16][(ks << 5) + ks8];
        const __bf16* wp = W2f + ((size_t)(ks << 3) << 9) + lo8;
        #pragma unroll
        for (int nf = 0; nf < 8; ++nf) {
            bf16x8 b = *(const bf16x8*)(wp + (nf << 9));
            acc2[0][nf] = __builtin_amdgcn_mfma_f32_16x16x32_bf16(a0, b, acc2[0][nf], 0, 0, 0);
            acc2[1][nf] = __builtin_amdgcn_mfma_f32_16x16x32_bf16(a1, b, acc2[1][nf], 0, 0, 0);
        }
    }

    // ---- bias + LayerNorm + store + scatter-add ----
    float b2v[8], gv[8], bvv[8];
    #pragma unroll
    for (int nf = 0; nf < 8; ++nf) {
        b2v[nf] = b2[nf * 16 + c16];
        gv[nf]  = lng[nf * 16 + c16];
        bvv[nf] = lnb[nf * 16 + c16];
    }

    #pragma unroll
    for (int mi = 0; mi < 2; ++mi) {
        float s[4] = {0.f, 0.f, 0.f, 0.f}, q[4] = {0.f, 0.f, 0.f, 0.f};
        #pragma unroll
        for (int nf = 0; nf < 8; ++nf)
            #pragma unroll
            for (int r = 0; r < 4; ++r) {
                float zz = acc2[mi][nf][r] + b2v[nf];
                acc2[mi][nf][r] = zz;
                s[r] += zz;
                q[r] += zz * zz;
            }
        #pragma unroll
        for (int m = 1; m <= 8; m <<= 1)
            #pragma unroll
            for (int r = 0; r < 4; ++r) {
                s[r] += __shfl_xor(s[r], m, 64);
                q[r] += __shfl_xor(q[r], m, 64);
            }
        #pragma unroll
        for (int r = 0; r < 4; ++r) {
            const float mu   = s[r] * (1.0f / 128.0f);
            const float var  = q[r] * (1.0f / 128.0f) - mu * mu;
            const float rstd = rsqrtf(var + LN_EPS);
            const int row = wrow0 + mi * 16 + kq * 4 + r;
            const int ge  = e0g + row;
            if (ge < NEDGES) {
                const size_t erow = (size_t)ge * D;
                float* ap = agg + (size_t)dst_s[row] * D;
                #pragma unroll
                for (int nf = 0; nf < 8; ++nf) {
                    const int col = nf * 16 + c16;
                    float o = (acc2[mi][nf][r] - mu) * rstd * gv[nf] + bvv[nf];
                    edges_out[erow + col] = o;
                    atomicAdd(ap + col, o);
                }
            }
        }
    }
}

// ---------------------------------------------------------------------------
// Node kernel (bf16 MFMA): 64 nodes/block; in = [x, agg] (256)
// ---------------------------------------------------------------------------
__global__ __launch_bounds__(BLK) void node_kernel(
    const float* __restrict__ x,
    const float* __restrict__ agg,
    const __bf16* __restrict__ W1f,
    const float* __restrict__ b1,
    const __bf16* __restrict__ W2f,
    const float* __restrict__ b2,
    const float* __restrict__ lng, const float* __restrict__ lnb,
    float* __restrict__ nodes_out)
{
    __shared__ __bf16 in_t[TN][264];   // 256 used; h1 aliases cols 0..127

    const int tid = threadIdx.x;
    const int r0g = blockIdx.x * TN;

    #pragma unroll
    for (int it = 0; it < 8; ++it) {
        const int idx = tid + it * BLK;
        const int e   = idx >> 5;
        const int c4  = (idx & 31) << 2;
        const int row = r0g + e;
        fx4 v = {0.f, 0.f, 0.f, 0.f};
        if (row < NNODES) v = *(const fx4*)&x[(size_t)row * D + c4];
        bf16x4 h;
        #pragma unroll
        for (int j = 0; j < 4; ++j) h[j] = (__bf16)v[j];
        *(bf16x4*)&in_t[e][c4] = h;
    }
    #pragma unroll
    for (int it = 0; it < 8; ++it) {
        const int idx = tid + it * BLK;
        const int e   = idx >> 5;
        const int c4  = (idx & 31) << 2;
        const int row = r0g + e;
        fx4 v = {0.f, 0.f, 0.f, 0.f};
        if (row < NNODES) v = *(const fx4*)&agg[(size_t)row * D + c4];
        bf16x4 h;
        #pragma unroll
        for (int j = 0; j < 4; ++j) h[j] = (__bf16)v[j];
        *(bf16x4*)&in_t[e][128 + c4] = h;
    }
    __syncthreads();

    const int lane  = tid & 63;
    const int wid   = tid >> 6;
    const int wrow0 = wid << 4;
    const int c16   = lane & 15;
    const int kq    = lane >> 4;
    const int ks8   = kq << 3;
    const int lo8   = lane << 3;

    // ---- GEMM1: [16,256] @ [256,128] ----
    f32x4 acc[8];
    #pragma unroll
    for (int nf = 0; nf < 8; ++nf) acc[nf] = (f32x4){0.f, 0.f, 0.f, 0.f};

    #pragma unroll
    for (int ks = 0; ks < 8; ++ks) {
        bf16x8 a = *(const bf16x8*)&in_t[wrow0 + c16][(ks << 5) + ks8];
        const __bf16* wp = W1f + ((size_t)(ks << 3) << 9) + lo8;
        #pragma unroll
        for (int nf = 0; nf < 8; ++nf) {
            bf16x8 b = *(const bf16x8*)(wp + (nf << 9));
            acc[nf] = __builtin_amdgcn_mfma_f32_16x16x32_bf16(a, b, acc[nf], 0, 0, 0);
        }
    }

    #pragma unroll
    for (int nf = 0; nf < 8; ++nf) {
        const float bb = b1[nf * 16 + c16];
        #pragma unroll
        for (int r = 0; r < 4; ++r) {
            float h = silu_f(acc[nf][r] + bb);
            in_t[wrow0 + kq * 4 + r][nf * 16 + c16] = (__bf16)h;
        }
    }

    // ---- GEMM2 ----
    f32x4 acc2[8];
    #pragma unroll
    for (int nf = 0; nf < 8; ++nf) acc2[nf] = (f32x4){0.f, 0.f, 0.f, 0.f};

    #pragma unroll
    for (int ks = 0; ks < 4; ++ks) {
        bf16x8 a = *(const bf16x8*)&in_t[wrow0 + c16][(ks << 5) + ks8];
        const __bf16* wp = W2f + ((size_t)(ks << 3) << 9) + lo8;
        #pragma unroll
        for (int nf = 0; nf < 8; ++nf) {
            bf16x8 b = *(const bf16x8*)(wp + (nf << 9));
            acc2[nf] = __builtin_amdgcn_mfma_f32_16x16x32_bf16(a, b, acc2[nf], 0, 0, 0);
        }
    }

    // ---- bias + LN + residual + store ----
    float b2v[8], gv[8], bvv[8];
    #pragma unroll
    for (int nf = 0; nf < 8; ++nf) {
        b2v[nf] = b2[nf * 16 + c16];
        gv[nf]  = lng[nf * 16 + c16];
        bvv[nf] = lnb[nf * 16 + c16];
    }

    float s[4] = {0.f, 0.f, 0.f, 0.f}, q[4] = {0.f, 0.f, 0.f, 0.f};
    #pragma unroll
    for (int nf = 0; nf < 8; ++nf)
        #pragma unroll
        for (int r = 0; r < 4; ++r) {
            float zz = acc2[nf][r] + b2v[nf];
            acc2[nf][r] = zz;
            s[r] += zz;
            q[r] += zz * zz;
        }
    #pragma unroll
    for (int m = 1; m <= 8; m <<= 1)
        #pragma unroll
        for (int r = 0; r < 4; ++r) {
            s[r] += __shfl_xor(s[r], m, 64);
            q[r] += __shfl_xor(q[r], m, 64);
        }

    #pragma unroll
    for (int r = 0; r < 4; ++r) {
        const float mu   = s[r] * (1.0f / 128.0f);
        const float var  = q[r] * (1.0f / 128.0f) - mu * mu;
        const float rstd = rsqrtf(var + LN_EPS);
        const int row = r0g + wrow0 + kq * 4 + r;
        if (row >= NNODES) continue;
        const size_t orow = (size_t)row * D;
        #pragma unroll
        for (int nf = 0; nf < 8; ++nf) {
            const int col = nf * 16 + c16;
            float o = (acc2[nf][r] - mu) * rstd * gv[nf] + bvv[nf] + x[orow + col];
            nodes_out[orow + col] = o;
        }
    }
}

extern "C" void kernel_launch(void* const* d_in, const int* in_sizes, int n_in,
                              void* d_out, int out_size, void* d_ws, size_t ws_size,
                              hipStream_t stream) {
    (void)in_sizes; (void)n_in; (void)ws_size; (void)out_size;

    const float* x         = (const float*)d_in[0];
    const float* edge_attr = (const float*)d_in[1];
    const int*   edge_idx  = (const int*)  d_in[2];
    const float* eW1 = (const float*)d_in[3];
    const float* eb1 = (const float*)d_in[4];
    const float* eW2 = (const float*)d_in[5];
    const float* eb2 = (const float*)d_in[6];
    const float* elg = (const float*)d_in[7];
    const float* elb = (const float*)d_in[8];
    const float* nW1 = (const float*)d_in[9];
    const float* nb1 = (const float*)d_in[10];
    const float* nW2 = (const float*)d_in[11];
    const float* nb2 = (const float*)d_in[12];
    const float* nlg = (const float*)d_in[13];
    const float* nlb = (const float*)d_in[14];

    float* out       = (float*)d_out;
    float* nodes_out = out;                        // doubles as agg accumulator
    float* edges_out = out + (size_t)NNODES * D;

    __bf16* ws = (__bf16*)d_ws;

    prep_weights<<<(WS_ELEMS + 255) / 256, 256, 0, stream>>>(eW1, eW2, nW1, nW2, ws);

    hipMemsetAsync(nodes_out, 0, (size_t)NNODES * D * sizeof(float), stream);

    edge_kernel<<<(NEDGES + TEE - 1) / TEE, BLK, 0, stream>>>(
        x, edge_attr, edge_idx,
        ws + EW1F_OFF, eb1, ws + EW2F_OFF, eb2, elg, elb,
        edges_out, nodes_out);

    node_kernel<<<(NNODES + TN - 1) / TN, BLK, 0, stream>>>(
        x, nodes_out,
        ws + NW1F_OFF, nb1, ws + NW2F_OFF, nb2, nlg, nlb,
        nodes_out);
}

// Round 6
// 444.966 us; speedup vs baseline: 1.4184x; 1.4184x over previous
//
#include <hip/hip_runtime.h>

#define D       128
#define NNODES  50000
#define NEDGES  600000
#define TE      64           // edges per block (edge kernel); 600000 % 64 == 0... (9375 blocks)
#define TN      64           // nodes per block (node kernel)
#define BLK     256
#define LN_EPS  1e-5f

typedef float  fx4    __attribute__((ext_vector_type(4)));
typedef float  f32x4  __attribute__((ext_vector_type(4)));
typedef __bf16 bf16x4 __attribute__((ext_vector_type(4)));
typedef __bf16 bf16x8 __attribute__((ext_vector_type(8)));

// ---- d_ws layout (bf16 elements) ----
// Fragment-major weights: frag[kstep][nf][lane(64)][8], 512 bf16 per frag.
#define EW1F_OFF 0                         // K=384: 12 ksteps * 8 nf
#define EW2F_OFF (128 * 384)               // K=128:  4 ksteps * 8 nf
#define NW1F_OFF (EW2F_OFF + 128 * 128)    // K=256:  8 ksteps * 8 nf
#define NW2F_OFF (NW1F_OFF + 128 * 256)    // K=128
#define WS_ELEMS (NW2F_OFF + 128 * 128)    // 114688 bf16

__device__ __forceinline__ float silu_f(float z) {
    return z * (1.0f / (1.0f + __expf(-z)));
}

// ---------------------------------------------------------------------------
// Weight prep: f32 [K][128] -> bf16 fragment-major.
// frag f = ks*8+nf ; lane l ; elem j  maps to  n = nf*16+(l&15),
// k = ks*32 + (l>>4)*8 + j.  Stored at  base + f*512 + l*8 + j.
// ---------------------------------------------------------------------------
__global__ __launch_bounds__(256) void prep_weights(
    const float* __restrict__ eW1, const float* __restrict__ eW2,
    const float* __restrict__ nW1, const float* __restrict__ nW2,
    __bf16* __restrict__ ws)
{
    int idx = blockIdx.x * 256 + threadIdx.x;
    if (idx >= WS_ELEMS) return;
    const float* src;
    int local;
    if (idx < EW2F_OFF)      { src = eW1; local = idx; }
    else if (idx < NW1F_OFF) { src = eW2; local = idx - EW2F_OFF; }
    else if (idx < NW2F_OFF) { src = nW1; local = idx - NW1F_OFF; }
    else                     { src = nW2; local = idx - NW2F_OFF; }
    const int f   = local >> 9;          // frag index
    const int rem = local & 511;
    const int l   = rem >> 3;            // lane
    const int j   = rem & 7;             // elem
    const int ks  = f >> 3;
    const int nf  = f & 7;
    const int n   = (nf << 4) + (l & 15);
    const int k   = (ks << 5) + ((l >> 4) << 3) + j;
    ws[idx] = (__bf16)src[(size_t)k * D + n];
}

// ---------------------------------------------------------------------------
// Edge kernel: 64 edges/block, 4 waves x 16 rows. Round-4 structure, but:
//  - LDS holds only [x[dst] | x[src]] (256 cols) -> 33.8 KB -> 4 blocks/CU
//  - edge_attr A-fragments built directly from global into registers
//  - h1 aliases in_t cols 0..127 (wave-private rows, no barrier)
// ---------------------------------------------------------------------------
__global__ __launch_bounds__(BLK, 4) void edge_kernel(
    const float* __restrict__ x,
    const float* __restrict__ edge_attr,
    const int*   __restrict__ edge_index,
    const __bf16* __restrict__ W1f,
    const float* __restrict__ b1,
    const __bf16* __restrict__ W2f,
    const float* __restrict__ b2,
    const float* __restrict__ lng, const float* __restrict__ lnb,
    float* __restrict__ edges_out,
    float* __restrict__ agg)
{
    __shared__ __bf16 in_t[TE][264];   // 256 used; h1 aliases cols 0..127 later
    __shared__ int    src_s[TE], dst_s[TE];

    const int tid = threadIdx.x;
    const int e0g = blockIdx.x * TE;

    if (tid < TE) {
        src_s[tid] = edge_index[e0g + tid];            // edge_index[0] = src (j)
        dst_s[tid] = edge_index[NEDGES + e0g + tid];   // edge_index[1] = dst (i)
    }
    __syncthreads();

    const int lane  = tid & 63;
    const int wid   = tid >> 6;
    const int wrow0 = wid << 4;        // wave's 16 rows
    const int c16   = lane & 15;
    const int kq    = lane >> 4;
    const int ks8   = kq << 3;
    const int lo8   = lane << 3;       // fragment lane offset (bf16 elems)

    // ---- edge_attr A-fragments straight from global (block-contiguous rows) ----
    bf16x8 aE[4];
    {
        const float* ep = edge_attr + (size_t)(e0g + wrow0 + c16) * D + ks8;
        #pragma unroll
        for (int ks2 = 0; ks2 < 4; ++ks2) {
            fx4 v0 = *(const fx4*)(ep + (ks2 << 5));
            fx4 v1 = *(const fx4*)(ep + (ks2 << 5) + 4);
            bf16x8 a;
            #pragma unroll
            for (int j = 0; j < 4; ++j) { a[j] = (__bf16)v0[j]; a[j + 4] = (__bf16)v1[j]; }
            aE[ks2] = a;
        }
    }

    // ---- stage x[dst] | x[src] (2 segments x 64 rows x 32 fx4) ----
    #pragma unroll
    for (int it = 0; it < 8; ++it) {
        const int idx = tid + it * BLK;
        const int e   = idx >> 5;
        const int c4  = (idx & 31) << 2;
        fx4 v = *(const fx4*)&x[(size_t)dst_s[e] * D + c4];
        bf16x4 h;
        #pragma unroll
        for (int j = 0; j < 4; ++j) h[j] = (__bf16)v[j];
        *(bf16x4*)&in_t[e][c4] = h;
    }
    #pragma unroll
    for (int it = 0; it < 8; ++it) {
        const int idx = tid + it * BLK;
        const int e   = idx >> 5;
        const int c4  = (idx & 31) << 2;
        fx4 v = *(const fx4*)&x[(size_t)src_s[e] * D + c4];
        bf16x4 h;
        #pragma unroll
        for (int j = 0; j < 4; ++j) h[j] = (__bf16)v[j];
        *(bf16x4*)&in_t[e][128 + c4] = h;
    }
    __syncthreads();

    // ---- GEMM1: [16,384] @ [384,128] per wave ----
    f32x4 acc[8];
    #pragma unroll
    for (int nf = 0; nf < 8; ++nf) acc[nf] = (f32x4){0.f, 0.f, 0.f, 0.f};

    #pragma unroll
    for (int ks = 0; ks < 12; ++ks) {
        bf16x8 a = (ks < 8) ? *(const bf16x8*)&in_t[wrow0 + c16][(ks << 5) + ks8]
                            : aE[ks - 8];
        const __bf16* wp = W1f + ((size_t)(ks << 3) << 9) + lo8;
        #pragma unroll
        for (int nf = 0; nf < 8; ++nf) {
            bf16x8 b = *(const bf16x8*)(wp + (nf << 9));
            acc[nf] = __builtin_amdgcn_mfma_f32_16x16x32_bf16(a, b, acc[nf], 0, 0, 0);
        }
    }

    // SiLU + bias -> h1 aliased into in_t cols 0..127 (wave-private rows;
    // per-wave in-order LDS makes read-before-write safe without a barrier)
    #pragma unroll
    for (int nf = 0; nf < 8; ++nf) {
        const float bb = b1[nf * 16 + c16];
        #pragma unroll
        for (int r = 0; r < 4; ++r) {
            float h = silu_f(acc[nf][r] + bb);
            in_t[wrow0 + kq * 4 + r][nf * 16 + c16] = (__bf16)h;
        }
    }

    // ---- GEMM2: [16,128] @ [128,128] per wave ----
    f32x4 acc2[8];
    #pragma unroll
    for (int nf = 0; nf < 8; ++nf) acc2[nf] = (f32x4){0.f, 0.f, 0.f, 0.f};

    #pragma unroll
    for (int ks = 0; ks < 4; ++ks) {
        bf16x8 a = *(const bf16x8*)&in_t[wrow0 + c16][(ks << 5) + ks8];
        const __bf16* wp = W2f + ((size_t)(ks << 3) << 9) + lo8;
        #pragma unroll
        for (int nf = 0; nf < 8; ++nf) {
            bf16x8 b = *(const bf16x8*)(wp + (nf << 9));
            acc2[nf] = __builtin_amdgcn_mfma_f32_16x16x32_bf16(a, b, acc2[nf], 0, 0, 0);
        }
    }

    // ---- bias + LayerNorm + store + scatter-add ----
    float b2v[8], gv[8], bvv[8];
    #pragma unroll
    for (int nf = 0; nf < 8; ++nf) {
        b2v[nf] = b2[nf * 16 + c16];
        gv[nf]  = lng[nf * 16 + c16];
        bvv[nf] = lnb[nf * 16 + c16];
    }

    float s[4] = {0.f, 0.f, 0.f, 0.f}, q[4] = {0.f, 0.f, 0.f, 0.f};
    #pragma unroll
    for (int nf = 0; nf < 8; ++nf)
        #pragma unroll
        for (int r = 0; r < 4; ++r) {
            float zz = acc2[nf][r] + b2v[nf];
            acc2[nf][r] = zz;
            s[r] += zz;
            q[r] += zz * zz;
        }
    #pragma unroll
    for (int m = 1; m <= 8; m <<= 1)
        #pragma unroll
        for (int r = 0; r < 4; ++r) {
            s[r] += __shfl_xor(s[r], m, 64);
            q[r] += __shfl_xor(q[r], m, 64);
        }

    #pragma unroll
    for (int r = 0; r < 4; ++r) {
        const float mu   = s[r] * (1.0f / 128.0f);
        const float var  = q[r] * (1.0f / 128.0f) - mu * mu;
        const float rstd = rsqrtf(var + LN_EPS);
        const int row = wrow0 + kq * 4 + r;
        const size_t erow = (size_t)(e0g + row) * D;
        float* ap = agg + (size_t)dst_s[row] * D;
        #pragma unroll
        for (int nf = 0; nf < 8; ++nf) {
            const int col = nf * 16 + c16;
            float o = (acc2[nf][r] - mu) * rstd * gv[nf] + bvv[nf];
            edges_out[erow + col] = o;
            atomicAdd(ap + col, o);
        }
    }
}

// ---------------------------------------------------------------------------
// Node kernel (bf16 MFMA): 64 nodes/block; in = [x, agg] (256)
// ---------------------------------------------------------------------------
__global__ __launch_bounds__(BLK, 4) void node_kernel(
    const float* __restrict__ x,
    const float* __restrict__ agg,
    const __bf16* __restrict__ W1f,
    const float* __restrict__ b1,
    const __bf16* __restrict__ W2f,
    const float* __restrict__ b2,
    const float* __restrict__ lng, const float* __restrict__ lnb,
    float* __restrict__ nodes_out)
{
    __shared__ __bf16 in_t[TN][264];   // 256 used; h1 aliases cols 0..127

    const int tid = threadIdx.x;
    const int r0g = blockIdx.x * TN;

    #pragma unroll
    for (int it = 0; it < 8; ++it) {
        const int idx = tid + it * BLK;
        const int e   = idx >> 5;
        const int c4  = (idx & 31) << 2;
        const int row = r0g + e;
        fx4 v = {0.f, 0.f, 0.f, 0.f};
        if (row < NNODES) v = *(const fx4*)&x[(size_t)row * D + c4];
        bf16x4 h;
        #pragma unroll
        for (int j = 0; j < 4; ++j) h[j] = (__bf16)v[j];
        *(bf16x4*)&in_t[e][c4] = h;
    }
    #pragma unroll
    for (int it = 0; it < 8; ++it) {
        const int idx = tid + it * BLK;
        const int e   = idx >> 5;
        const int c4  = (idx & 31) << 2;
        const int row = r0g + e;
        fx4 v = {0.f, 0.f, 0.f, 0.f};
        if (row < NNODES) v = *(const fx4*)&agg[(size_t)row * D + c4];
        bf16x4 h;
        #pragma unroll
        for (int j = 0; j < 4; ++j) h[j] = (__bf16)v[j];
        *(bf16x4*)&in_t[e][128 + c4] = h;
    }
    __syncthreads();

    const int lane  = tid & 63;
    const int wid   = tid >> 6;
    const int wrow0 = wid << 4;
    const int c16   = lane & 15;
    const int kq    = lane >> 4;
    const int ks8   = kq << 3;
    const int lo8   = lane << 3;

    // ---- GEMM1: [16,256] @ [256,128] ----
    f32x4 acc[8];
    #pragma unroll
    for (int nf = 0; nf < 8; ++nf) acc[nf] = (f32x4){0.f, 0.f, 0.f, 0.f};

    #pragma unroll
    for (int ks = 0; ks < 8; ++ks) {
        bf16x8 a = *(const bf16x8*)&in_t[wrow0 + c16][(ks << 5) + ks8];
        const __bf16* wp = W1f + ((size_t)(ks << 3) << 9) + lo8;
        #pragma unroll
        for (int nf = 0; nf < 8; ++nf) {
            bf16x8 b = *(const bf16x8*)(wp + (nf << 9));
            acc[nf] = __builtin_amdgcn_mfma_f32_16x16x32_bf16(a, b, acc[nf], 0, 0, 0);
        }
    }

    #pragma unroll
    for (int nf = 0; nf < 8; ++nf) {
        const float bb = b1[nf * 16 + c16];
        #pragma unroll
        for (int r = 0; r < 4; ++r) {
            float h = silu_f(acc[nf][r] + bb);
            in_t[wrow0 + kq * 4 + r][nf * 16 + c16] = (__bf16)h;
        }
    }

    // ---- GEMM2 ----
    f32x4 acc2[8];
    #pragma unroll
    for (int nf = 0; nf < 8; ++nf) acc2[nf] = (f32x4){0.f, 0.f, 0.f, 0.f};

    #pragma unroll
    for (int ks = 0; ks < 4; ++ks) {
        bf16x8 a = *(const bf16x8*)&in_t[wrow0 + c16][(ks << 5) + ks8];
        const __bf16* wp = W2f + ((size_t)(ks << 3) << 9) + lo8;
        #pragma unroll
        for (int nf = 0; nf < 8; ++nf) {
            bf16x8 b = *(const bf16x8*)(wp + (nf << 9));
            acc2[nf] = __builtin_amdgcn_mfma_f32_16x16x32_bf16(a, b, acc2[nf], 0, 0, 0);
        }
    }

    // ---- bias + LN + residual + store ----
    float b2v[8], gv[8], bvv[8];
    #pragma unroll
    for (int nf = 0; nf < 8; ++nf) {
        b2v[nf] = b2[nf * 16 + c16];
        gv[nf]  = lng[nf * 16 + c16];
        bvv[nf] = lnb[nf * 16 + c16];
    }

    float s[4] = {0.f, 0.f, 0.f, 0.f}, q[4] = {0.f, 0.f, 0.f, 0.f};
    #pragma unroll
    for (int nf = 0; nf < 8; ++nf)
        #pragma unroll
        for (int r = 0; r < 4; ++r) {
            float zz = acc2[nf][r] + b2v[nf];
            acc2[nf][r] = zz;
            s[r] += zz;
            q[r] += zz * zz;
        }
    #pragma unroll
    for (int m = 1; m <= 8; m <<= 1)
        #pragma unroll
        for (int r = 0; r < 4; ++r) {
            s[r] += __shfl_xor(s[r], m, 64);
            q[r] += __shfl_xor(q[r], m, 64);
        }

    #pragma unroll
    for (int r = 0; r < 4; ++r) {
        const float mu   = s[r] * (1.0f / 128.0f);
        const float var  = q[r] * (1.0f / 128.0f) - mu * mu;
        const float rstd = rsqrtf(var + LN_EPS);
        const int row = r0g + wrow0 + kq * 4 + r;
        if (row >= NNODES) continue;
        const size_t orow = (size_t)row * D;
        #pragma unroll
        for (int nf = 0; nf < 8; ++nf) {
            const int col = nf * 16 + c16;
            float o = (acc2[nf][r] - mu) * rstd * gv[nf] + bvv[nf] + x[orow + col];
            nodes_out[orow + col] = o;
        }
    }
}

extern "C" void kernel_launch(void* const* d_in, const int* in_sizes, int n_in,
                              void* d_out, int out_size, void* d_ws, size_t ws_size,
                              hipStream_t stream) {
    (void)in_sizes; (void)n_in; (void)ws_size; (void)out_size;

    const float* x         = (const float*)d_in[0];
    const float* edge_attr = (const float*)d_in[1];
    const int*   edge_idx  = (const int*)  d_in[2];
    const float* eW1 = (const float*)d_in[3];
    const float* eb1 = (const float*)d_in[4];
    const float* eW2 = (const float*)d_in[5];
    const float* eb2 = (const float*)d_in[6];
    const float* elg = (const float*)d_in[7];
    const float* elb = (const float*)d_in[8];
    const float* nW1 = (const float*)d_in[9];
    const float* nb1 = (const float*)d_in[10];
    const float* nW2 = (const float*)d_in[11];
    const float* nb2 = (const float*)d_in[12];
    const float* nlg = (const float*)d_in[13];
    const float* nlb = (const float*)d_in[14];

    float* out       = (float*)d_out;
    float* nodes_out = out;                        // doubles as agg accumulator
    float* edges_out = out + (size_t)NNODES * D;

    __bf16* ws = (__bf16*)d_ws;

    prep_weights<<<(WS_ELEMS + 255) / 256, 256, 0, stream>>>(eW1, eW2, nW1, nW2, ws);

    hipMemsetAsync(nodes_out, 0, (size_t)NNODES * D * sizeof(float), stream);

    edge_kernel<<<NEDGES / TE, BLK, 0, stream>>>(
        x, edge_attr, edge_idx,
        ws + EW1F_OFF, eb1, ws + EW2F_OFF, eb2, elg, elb,
        edges_out, nodes_out);

    node_kernel<<<(NNODES + TN - 1) / TN, BLK, 0, stream>>>(
        x, nodes_out,
        ws + NW1F_OFF, nb1, ws + NW2F_OFF, nb2, nlg, nlb,
        nodes_out);
}